// Round 1
// baseline (123.846 us; speedup 1.0000x reference)
//
#include <hip/hip_runtime.h>
#include <math.h>

#define N_BANK   1281167
#define NEGS     4096
#define K_TOT    (NEGS + 1)      // 4097
#define PROJ_DIM 128
#define BATCH    256
#define CHUNKS   8               // k-chunks per batch row -> 2048 blocks

// ---------------------------------------------------------------------------
// Pass 1: gather bank rows, dot with proj, exp, store exp values, accumulate
// global sum (for z). Also emits pos_samples (k==0 rows) directly from the
// already-loaded registers.
// Block layout: blockIdx = b*CHUNKS + chunk. 256 threads = 16 groups of 16
// lanes; each group handles one (b,k) pair per iteration; each lane owns 8
// consecutive floats of the 128-dim row (2x float4 = 32B, coalesced).
// ---------------------------------------------------------------------------
__global__ __launch_bounds__(256) void npid_main(
    const float* __restrict__ proj, const float* __restrict__ bank,
    const int* __restrict__ idx, float* __restrict__ out,
    float* __restrict__ expv, double* __restrict__ accum)
{
    const int b     = blockIdx.x / CHUNKS;
    const int chunk = blockIdx.x % CHUNKS;
    const int tid   = threadIdx.x;
    const int group = tid >> 4;   // 0..15
    const int lane  = tid & 15;   // 0..15

    // proj fragment for this block's b (L1/L2 hit, loaded once)
    const float* pr = proj + b * PROJ_DIM + lane * 8;
    float4 p0 = *(const float4*)(pr);
    float4 p1 = *(const float4*)(pr + 4);

    const int KCH = (K_TOT + CHUNKS - 1) / CHUNKS;   // 513
    const int k0  = chunk * KCH;
    const int k1  = (k0 + KCH < K_TOT) ? (k0 + KCH) : K_TOT;

    double dsum = 0.0;

    for (int k = k0 + group; k < k1; k += 16) {
        const int row = idx[b * K_TOT + k];
        const float* br = bank + (long long)row * PROJ_DIM + lane * 8;
        float4 b0 = *(const float4*)(br);
        float4 b1 = *(const float4*)(br + 4);

        float s = p0.x*b0.x + p0.y*b0.y + p0.z*b0.z + p0.w*b0.w
                + p1.x*b1.x + p1.y*b1.y + p1.z*b1.z + p1.w*b1.w;

        // butterfly reduce across the 16-lane group (stays inside the group)
        s += __shfl_xor(s, 1);
        s += __shfl_xor(s, 2);
        s += __shfl_xor(s, 4);
        s += __shfl_xor(s, 8);

        if (k == 0) {
            // pos_samples: exact copy of the gathered bank row
            *(float4*)(out + 1 + b * PROJ_DIM + lane * 8)     = b0;
            *(float4*)(out + 1 + b * PROJ_DIM + lane * 8 + 4) = b1;
        }

        if (lane == 0) {
            float e = expf(s * (1.0f / 0.07f));
            expv[b * K_TOT + k] = e;
            dsum += (double)e;
        }
    }

    // block reduction of dsum -> one double atomic per block
    __shared__ double sred[256];
    sred[tid] = dsum;
    __syncthreads();
    for (int off = 128; off > 0; off >>= 1) {
        if (tid < off) sred[tid] += sred[tid + off];
        __syncthreads();
    }
    if (tid == 0) atomicAdd(accum, sred[0]);
}

// ---------------------------------------------------------------------------
// Pass 2: read stored exp values, compute loss terms with cancellation-free
// log1p forms, reduce to a double accumulator.
//   z  = mean(exp) * N;  mz = m * z  (m = NEGS/N)
//   k==0: p_d = log(o/(o+mz))  = -log1p(mz/o)
//   k>=1: p_n = log(mz/(o+mz)) = -log1p(o/mz)
// ---------------------------------------------------------------------------
__global__ __launch_bounds__(256) void npid_loss(
    const float* __restrict__ expv, const double* __restrict__ accum,
    double* __restrict__ lossacc)
{
    const double z  = (accum[0] / (double)(BATCH * K_TOT)) * (double)N_BANK;
    const double mz = ((double)NEGS / (double)N_BANK) * z;

    double local = 0.0;
    const int total = BATCH * K_TOT;
    for (int i = blockIdx.x * blockDim.x + threadIdx.x; i < total;
         i += gridDim.x * blockDim.x) {
        const int k = i % K_TOT;
        const double o = (double)expv[i];
        local += (k == 0) ? -log1p(mz / o) : -log1p(o / mz);
    }

    __shared__ double sred[256];
    const int tid = threadIdx.x;
    sred[tid] = local;
    __syncthreads();
    for (int off = 128; off > 0; off >>= 1) {
        if (tid < off) sred[tid] += sred[tid + off];
        __syncthreads();
    }
    if (tid == 0) atomicAdd(lossacc, sred[0]);
}

__global__ void npid_init(double* __restrict__ accum)
{
    if (threadIdx.x < 2) accum[threadIdx.x] = 0.0;
}

__global__ void npid_final(const double* __restrict__ lossacc,
                           float* __restrict__ out)
{
    if (threadIdx.x == 0 && blockIdx.x == 0)
        out[0] = (float)(-lossacc[0] / (double)BATCH);
}

extern "C" void kernel_launch(void* const* d_in, const int* in_sizes, int n_in,
                              void* d_out, int out_size, void* d_ws, size_t ws_size,
                              hipStream_t stream)
{
    const float* proj = (const float*)d_in[0];
    const float* bank = (const float*)d_in[1];
    const int*   idx  = (const int*)d_in[2];
    float* out = (float*)d_out;

    // ws layout: [0..15] two double accumulators (sum_exp, loss), then exp array
    double* accum = (double*)d_ws;
    float*  expv  = (float*)((char*)d_ws + 16);

    npid_init <<<1, 64, 0, stream>>>(accum);
    npid_main <<<BATCH * CHUNKS, 256, 0, stream>>>(proj, bank, idx, out, expv, accum);
    npid_loss <<<1024, 256, 0, stream>>>(expv, accum, accum + 1);
    npid_final<<<1, 64, 0, stream>>>(accum + 1, out);
}

// Round 2
// 107.860 us; speedup vs baseline: 1.1482x; 1.1482x over previous
//
#include <hip/hip_runtime.h>
#include <math.h>

#define N_BANK   1281167
#define NEGS     4096
#define K_TOT    (NEGS + 1)      // 4097
#define PROJ_DIM 128
#define BATCH    256
#define CHUNKS   8               // k-chunks per batch row -> 2048 blocks
#define KCH      ((K_TOT + CHUNKS - 1) / CHUNKS)   // 513

// ---------------------------------------------------------------------------
// Pass 1: gather bank rows, dot with proj, exp, store exp, accumulate sum(e).
// idx staged in LDS (removes the per-iteration dependent idx load).
// Row split into halves: lane L owns floats [4L,4L+4) and [64+4L,64+4L+4),
// so every wave load instruction is a fully-contiguous 256B-per-group segment.
// 2x manual unroll: 4 gathers in flight per group before any reduction.
// ---------------------------------------------------------------------------
__global__ __launch_bounds__(256) void npid_main(
    const float* __restrict__ proj, const float* __restrict__ bank,
    const int* __restrict__ idx, float* __restrict__ out,
    float* __restrict__ expv, double* __restrict__ accum)
{
    const int b     = blockIdx.x / CHUNKS;
    const int chunk = blockIdx.x % CHUNKS;
    const int tid   = threadIdx.x;
    const int group = tid >> 4;   // 0..15
    const int lane  = tid & 15;   // 0..15

    __shared__ int    sidx[KCH];
    __shared__ double sred[256];

    const int k0     = chunk * KCH;
    const int kcount = (k0 + KCH <= K_TOT) ? KCH : (K_TOT - k0);

    for (int t = tid; t < kcount; t += 256)
        sidx[t] = idx[b * K_TOT + k0 + t];
    __syncthreads();

    const float* pr = proj + b * PROJ_DIM;
    float4 p0 = *(const float4*)(pr + 4 * lane);
    float4 p1 = *(const float4*)(pr + 64 + 4 * lane);

    double dsum = 0.0;
    int j = group;
    for (; j + 16 < kcount; j += 32) {
        const int r0 = sidx[j];
        const int r1 = sidx[j + 16];
        const float* br0 = bank + (long long)r0 * PROJ_DIM;
        const float* br1 = bank + (long long)r1 * PROJ_DIM;
        float4 a0 = *(const float4*)(br0 + 4 * lane);
        float4 a1 = *(const float4*)(br0 + 64 + 4 * lane);
        float4 c0 = *(const float4*)(br1 + 4 * lane);
        float4 c1 = *(const float4*)(br1 + 64 + 4 * lane);

        float s0 = p0.x*a0.x + p0.y*a0.y + p0.z*a0.z + p0.w*a0.w
                 + p1.x*a1.x + p1.y*a1.y + p1.z*a1.z + p1.w*a1.w;
        float s1 = p0.x*c0.x + p0.y*c0.y + p0.z*c0.z + p0.w*c0.w
                 + p1.x*c1.x + p1.y*c1.y + p1.z*c1.z + p1.w*c1.w;

        s0 += __shfl_xor(s0, 1);  s1 += __shfl_xor(s1, 1);
        s0 += __shfl_xor(s0, 2);  s1 += __shfl_xor(s1, 2);
        s0 += __shfl_xor(s0, 4);  s1 += __shfl_xor(s1, 4);
        s0 += __shfl_xor(s0, 8);  s1 += __shfl_xor(s1, 8);

        if (lane == 0) {
            float e0 = expf(s0 * (1.0f / 0.07f));
            float e1 = expf(s1 * (1.0f / 0.07f));
            expv[b * K_TOT + k0 + j]      = e0;
            expv[b * K_TOT + k0 + j + 16] = e1;
            dsum += (double)e0 + (double)e1;
        }
    }
    if (j < kcount) {                      // tail (at most one per group)
        const int r0 = sidx[j];
        const float* br0 = bank + (long long)r0 * PROJ_DIM;
        float4 a0 = *(const float4*)(br0 + 4 * lane);
        float4 a1 = *(const float4*)(br0 + 64 + 4 * lane);
        float s0 = p0.x*a0.x + p0.y*a0.y + p0.z*a0.z + p0.w*a0.w
                 + p1.x*a1.x + p1.y*a1.y + p1.z*a1.z + p1.w*a1.w;
        s0 += __shfl_xor(s0, 1);
        s0 += __shfl_xor(s0, 2);
        s0 += __shfl_xor(s0, 4);
        s0 += __shfl_xor(s0, 8);
        if (lane == 0) {
            float e0 = expf(s0 * (1.0f / 0.07f));
            expv[b * K_TOT + k0 + j] = e0;
            dsum += (double)e0;
        }
    }

    // pos_samples: exact copy of the k==0 gathered row (cache-hot re-read)
    if (chunk == 0 && group == 0) {
        const int row = sidx[0];
        const float* br = bank + (long long)row * PROJ_DIM;
        *(float4*)(out + 1 + b * PROJ_DIM + 4 * lane)      = *(const float4*)(br + 4 * lane);
        *(float4*)(out + 1 + b * PROJ_DIM + 64 + 4 * lane) = *(const float4*)(br + 64 + 4 * lane);
    }

    sred[tid] = dsum;
    __syncthreads();
    for (int off = 128; off > 0; off >>= 1) {
        if (tid < off) sred[tid] += sred[tid + off];
        __syncthreads();
    }
    if (tid == 0) atomicAdd(accum, sred[0]);
}

// ---------------------------------------------------------------------------
// Pass 2: one float4 + 4 log1pf per thread, generic p_n term for ALL entries
// (k==0 corrected in npid_final). p_n = -log1p(o/mz), cancellation-free.
// ---------------------------------------------------------------------------
__global__ __launch_bounds__(256) void npid_loss(
    const float* __restrict__ expv, const double* __restrict__ accum,
    double* __restrict__ lossacc)
{
    const double z  = (accum[0] / (double)(BATCH * K_TOT)) * (double)N_BANK;
    const double mz = ((double)NEGS / (double)N_BANK) * z;
    const float inv_mz = (float)(1.0 / mz);

    const int nvec = (BATCH * K_TOT) / 4;     // 262208 exactly
    const int i = blockIdx.x * blockDim.x + threadIdx.x;

    double local = 0.0;
    if (i < nvec) {
        float4 o = ((const float4*)expv)[i];
        float t = log1pf(o.x * inv_mz) + log1pf(o.y * inv_mz)
                + log1pf(o.z * inv_mz) + log1pf(o.w * inv_mz);
        local = -(double)t;
    }

    __shared__ double sred[256];
    const int tid = threadIdx.x;
    sred[tid] = local;
    __syncthreads();
    for (int off = 128; off > 0; off >>= 1) {
        if (tid < off) sred[tid] += sred[tid + off];
        __syncthreads();
    }
    if (tid == 0) atomicAdd(lossacc, sred[0]);
}

__global__ void npid_init(double* __restrict__ accum)
{
    if (threadIdx.x < 2) accum[threadIdx.x] = 0.0;
}

// k==0 correction (replace generic p_n with p_d) + final scale/store.
__global__ __launch_bounds__(256) void npid_final(
    const float* __restrict__ expv, const double* __restrict__ accum,
    const double* __restrict__ lossacc, float* __restrict__ out)
{
    const double z  = (accum[0] / (double)(BATCH * K_TOT)) * (double)N_BANK;
    const double mz = ((double)NEGS / (double)N_BANK) * z;

    const int b = threadIdx.x;               // 0..255
    const double o = (double)expv[b * K_TOT];
    // added earlier: p_n_gen = -log1p(o/mz); want p_d = -log1p(mz/o)
    double corr = log1p(o / mz) - log1p(mz / o);

    __shared__ double sred[256];
    sred[b] = corr;
    __syncthreads();
    for (int off = 128; off > 0; off >>= 1) {
        if (b < off) sred[b] += sred[b + off];
        __syncthreads();
    }
    if (b == 0)
        out[0] = (float)(-(lossacc[0] + sred[0]) / (double)BATCH);
}

extern "C" void kernel_launch(void* const* d_in, const int* in_sizes, int n_in,
                              void* d_out, int out_size, void* d_ws, size_t ws_size,
                              hipStream_t stream)
{
    const float* proj = (const float*)d_in[0];
    const float* bank = (const float*)d_in[1];
    const int*   idx  = (const int*)d_in[2];
    float* out = (float*)d_out;

    double* accum = (double*)d_ws;                    // [0]=sum_exp, [1]=loss
    float*  expv  = (float*)((char*)d_ws + 16);

    npid_init <<<1, 64, 0, stream>>>(accum);
    npid_main <<<BATCH * CHUNKS, 256, 0, stream>>>(proj, bank, idx, out, expv, accum);
    const int nvec = (BATCH * K_TOT) / 4;
    npid_loss <<<(nvec + 255) / 256, 256, 0, stream>>>(expv, accum, accum + 1);
    npid_final<<<1, 256, 0, stream>>>(expv, accum, accum + 1, out);
}

// Round 3
// 98.196 us; speedup vs baseline: 1.2612x; 1.0984x over previous
//
#include <hip/hip_runtime.h>
#include <math.h>

#define N_BANK   1281167
#define NEGS     4096
#define K_TOT    (NEGS + 1)      // 4097
#define PROJ_DIM 128
#define BATCH    256
#define CHUNKS   16              // k-chunks per batch row -> 4096 blocks
#define KCH      ((K_TOT + CHUNKS - 1) / CHUNKS)   // 257
#define GRID_MAIN (BATCH * CHUNKS)                 // 4096
#define NVEC     ((BATCH * K_TOT) / 4)             // 262208
#define GRID_LOSS ((NVEC + 255) / 256)             // 1025

// ws layout:
//   [0      .. 32767]  : double mainpart[4096]  (per-block sum of exp)
//   [32768  .. 49151]  : double losspart[2048]  (per-block loss partials, 1025 used)
//   [65536  .. ]       : float  expv[BATCH*K_TOT]
#define WS_MAINPART(ws) ((double*)(ws))
#define WS_LOSSPART(ws) ((double*)((char*)(ws) + 32768))
#define WS_EXPV(ws)     ((float*)((char*)(ws) + 65536))

__device__ __forceinline__ double block_reduce_bcast(double v, double* swred, int tid)
{
    // wave reduce (64 lanes)
    for (int off = 32; off > 0; off >>= 1) v += __shfl_down(v, off);
    if ((tid & 63) == 0) swred[tid >> 6] = v;
    __syncthreads();
    double r = swred[0] + swred[1] + swred[2] + swred[3];
    __syncthreads();   // allow swred reuse afterwards
    return r;
}

// ---------------------------------------------------------------------------
// Pass 1: gather bank rows, dot with proj, exp, store exp, per-block partial
// sum of exp -> mainpart[block]. No atomics, no init kernel needed.
// 16-lane groups; lane L owns floats [4L,4L+4) and [64+4L,64+4L+8/..): every
// wave load instruction covers fully-contiguous 256B-per-group segments.
// ---------------------------------------------------------------------------
__global__ __launch_bounds__(256) void npid_main(
    const float* __restrict__ proj, const float* __restrict__ bank,
    const int* __restrict__ idx, float* __restrict__ out,
    float* __restrict__ expv, double* __restrict__ mainpart)
{
    const int b     = blockIdx.x >> 4;
    const int chunk = blockIdx.x & 15;
    const int tid   = threadIdx.x;
    const int group = tid >> 4;   // 0..15
    const int lane  = tid & 15;   // 0..15

    __shared__ int    sidx[KCH];
    __shared__ double swred[4];

    const int k0     = chunk * KCH;
    const int kcount = (k0 + KCH <= K_TOT) ? KCH : (K_TOT - k0);

    for (int t = tid; t < kcount; t += 256)
        sidx[t] = idx[b * K_TOT + k0 + t];
    __syncthreads();

    const float* pr = proj + b * PROJ_DIM;
    float4 p0 = *(const float4*)(pr + 4 * lane);
    float4 p1 = *(const float4*)(pr + 64 + 4 * lane);

    double dsum = 0.0;
    int j = group;
    for (; j + 16 < kcount; j += 32) {
        const int r0 = sidx[j];
        const int r1 = sidx[j + 16];
        const float* br0 = bank + (long long)r0 * PROJ_DIM;
        const float* br1 = bank + (long long)r1 * PROJ_DIM;
        float4 a0 = *(const float4*)(br0 + 4 * lane);
        float4 a1 = *(const float4*)(br0 + 64 + 4 * lane);
        float4 c0 = *(const float4*)(br1 + 4 * lane);
        float4 c1 = *(const float4*)(br1 + 64 + 4 * lane);

        float s0 = p0.x*a0.x + p0.y*a0.y + p0.z*a0.z + p0.w*a0.w
                 + p1.x*a1.x + p1.y*a1.y + p1.z*a1.z + p1.w*a1.w;
        float s1 = p0.x*c0.x + p0.y*c0.y + p0.z*c0.z + p0.w*c0.w
                 + p1.x*c1.x + p1.y*c1.y + p1.z*c1.z + p1.w*c1.w;

        s0 += __shfl_xor(s0, 1);  s1 += __shfl_xor(s1, 1);
        s0 += __shfl_xor(s0, 2);  s1 += __shfl_xor(s1, 2);
        s0 += __shfl_xor(s0, 4);  s1 += __shfl_xor(s1, 4);
        s0 += __shfl_xor(s0, 8);  s1 += __shfl_xor(s1, 8);

        if (lane == 0) {
            float e0 = expf(s0 * (1.0f / 0.07f));
            float e1 = expf(s1 * (1.0f / 0.07f));
            expv[b * K_TOT + k0 + j]      = e0;
            expv[b * K_TOT + k0 + j + 16] = e1;
            dsum += (double)e0 + (double)e1;
        }
    }
    for (; j < kcount; j += 16) {          // tail
        const int r0 = sidx[j];
        const float* br0 = bank + (long long)r0 * PROJ_DIM;
        float4 a0 = *(const float4*)(br0 + 4 * lane);
        float4 a1 = *(const float4*)(br0 + 64 + 4 * lane);
        float s0 = p0.x*a0.x + p0.y*a0.y + p0.z*a0.z + p0.w*a0.w
                 + p1.x*a1.x + p1.y*a1.y + p1.z*a1.z + p1.w*a1.w;
        s0 += __shfl_xor(s0, 1);
        s0 += __shfl_xor(s0, 2);
        s0 += __shfl_xor(s0, 4);
        s0 += __shfl_xor(s0, 8);
        if (lane == 0) {
            float e0 = expf(s0 * (1.0f / 0.07f));
            expv[b * K_TOT + k0 + j] = e0;
            dsum += (double)e0;
        }
    }

    // pos_samples: exact copy of the k==0 gathered row (cache-hot re-read)
    if (chunk == 0 && group == 0) {
        const int row = sidx[0];
        const float* br = bank + (long long)row * PROJ_DIM;
        *(float4*)(out + 1 + b * PROJ_DIM + 4 * lane)      = *(const float4*)(br + 4 * lane);
        *(float4*)(out + 1 + b * PROJ_DIM + 64 + 4 * lane) = *(const float4*)(br + 64 + 4 * lane);
    }

    double bsum = block_reduce_bcast(dsum, swred, tid);
    if (tid == 0) mainpart[blockIdx.x] = bsum;
}

// ---------------------------------------------------------------------------
// Pass 2: each block re-derives z from mainpart (16KB, L2-hit), then one
// float4 + 4 log1pf per thread with the generic p_n = -log1p(o/mz) term for
// ALL entries (k==0 corrected in npid_final). Writes losspart[block].
// ---------------------------------------------------------------------------
__global__ __launch_bounds__(256) void npid_loss(
    const float* __restrict__ expv, const double* __restrict__ mainpart,
    double* __restrict__ losspart)
{
    const int tid = threadIdx.x;
    __shared__ double swred[4];

    double zs = 0.0;
    for (int t = tid; t < GRID_MAIN; t += 256) zs += mainpart[t];
    const double esum = block_reduce_bcast(zs, swred, tid);

    const double z  = (esum / (double)(BATCH * K_TOT)) * (double)N_BANK;
    const double mz = ((double)NEGS / (double)N_BANK) * z;
    const float inv_mz = (float)(1.0 / mz);

    const int i = blockIdx.x * 256 + tid;
    double local = 0.0;
    if (i < NVEC) {
        float4 o = ((const float4*)expv)[i];
        float t = log1pf(o.x * inv_mz) + log1pf(o.y * inv_mz)
                + log1pf(o.z * inv_mz) + log1pf(o.w * inv_mz);
        local = -(double)t;
    }

    double bsum = block_reduce_bcast(local, swred, tid);
    if (tid == 0) losspart[blockIdx.x] = bsum;
}

// ---------------------------------------------------------------------------
// Final: reduce losspart, apply k==0 correction (swap generic p_n for p_d),
// scale, store loss to out[0].
// ---------------------------------------------------------------------------
__global__ __launch_bounds__(256) void npid_final(
    const float* __restrict__ expv, const double* __restrict__ mainpart,
    const double* __restrict__ losspart, float* __restrict__ out)
{
    const int tid = threadIdx.x;
    __shared__ double swred[4];

    double zs = 0.0;
    for (int t = tid; t < GRID_MAIN; t += 256) zs += mainpart[t];
    const double esum = block_reduce_bcast(zs, swred, tid);

    const double z  = (esum / (double)(BATCH * K_TOT)) * (double)N_BANK;
    const double mz = ((double)NEGS / (double)N_BANK) * z;

    double lsum = 0.0;
    for (int t = tid; t < GRID_LOSS; t += 256) lsum += losspart[t];

    // k==0 correction for batch row tid: added p_n_gen = -log1p(o/mz),
    // want p_d = -log1p(mz/o)
    const double o = (double)expv[tid * K_TOT];
    lsum += log1p(o / mz) - log1p(mz / o);

    double total = block_reduce_bcast(lsum, swred, tid);
    if (tid == 0) out[0] = (float)(-total / (double)BATCH);
}

extern "C" void kernel_launch(void* const* d_in, const int* in_sizes, int n_in,
                              void* d_out, int out_size, void* d_ws, size_t ws_size,
                              hipStream_t stream)
{
    const float* proj = (const float*)d_in[0];
    const float* bank = (const float*)d_in[1];
    const int*   idx  = (const int*)d_in[2];
    float* out = (float*)d_out;

    double* mainpart = WS_MAINPART(d_ws);
    double* losspart = WS_LOSSPART(d_ws);
    float*  expv     = WS_EXPV(d_ws);

    npid_main <<<GRID_MAIN, 256, 0, stream>>>(proj, bank, idx, out, expv, mainpart);
    npid_loss <<<GRID_LOSS, 256, 0, stream>>>(expv, mainpart, losspart);
    npid_final<<<1, 256, 0, stream>>>(expv, mainpart, losspart, out);
}